// Round 4
// baseline (1311.565 us; speedup 1.0000x reference)
//
#include <hip/hip_runtime.h>
#include <hip/hip_bf16.h>

// SwiGLU MLP: out = down( silu(x@Wg^T + bg) * (x@Wu^T + bu) ) + bd
// M=4096 tokens, H=4096, I=11008. fp32 in/out, bf16 MFMA compute.
// GEMM: 256x256 tile, BK=32, 8 waves, 4-deep LDS ring, counted vmcnt(8),
// m201-style phases: {ds_read -> stage -> barrier -> lgkm(0) -> 16 MFMA -> barrier},
// B-frags register-reused across the two mh-phases, XOR-swizzled LDS,
// XCD-aware bijective block swizzle.

#define M_TOK 4096
#define HID   4096
#define INT_  11008

typedef __attribute__((ext_vector_type(8))) short bf16x8;
typedef __attribute__((ext_vector_type(4))) float f32x4;

__device__ __forceinline__ unsigned short f2bf(float f) {
    union { float f; unsigned int u; } a; a.f = f;
    unsigned int u = a.u;
    u += 0x7fff + ((u >> 16) & 1);   // RNE
    return (unsigned short)(u >> 16);
}

__device__ __forceinline__ float bf2f(unsigned short h) {
    union { unsigned int u; float f; } a; a.u = ((unsigned int)h) << 16;
    return a.f;
}

// ---------------- fp32 -> bf16 convert (vectorized, grid-stride) ----------------
__global__ void cvt_f32_bf16(const float* __restrict__ in, unsigned short* __restrict__ out, int n4) {
    int stride = gridDim.x * blockDim.x;
    for (int i = blockIdx.x * blockDim.x + threadIdx.x; i < n4; i += stride) {
        float4 v = ((const float4*)in)[i];
        ushort4 o;
        o.x = f2bf(v.x); o.y = f2bf(v.y); o.z = f2bf(v.z); o.w = f2bf(v.w);
        ((ushort4*)out)[i] = o;
    }
}

#define GLL(gsrc, ldst) \
    __builtin_amdgcn_global_load_lds( \
        (__attribute__((address_space(1))) void*)(gsrc), \
        (__attribute__((address_space(3))) void*)(ldst), 16, 0, 0)

// ---------------- 256x256-tile bf16 GEMM, C = A * B^T (+epilogue) ----------------
// A: M x K bf16 row-major; B: N x K bf16 row-major. M%256==0, N%256==0, K%32==0,
// grid divisible by 8, K/32 >= 4.
// EPI 0: bf16 (acc+bias); EPI 1: bf16 silu(g)*(acc+bias); EPI 2: fp32 (acc+bias)
template<int EPI>
__global__ __launch_bounds__(512, 2)
void gemm256(const unsigned short* __restrict__ A,
             const unsigned short* __restrict__ B,
             const float* __restrict__ bias,
             const unsigned short* __restrict__ gbuf,
             void* __restrict__ Cv,
             int M, int N, int K) {
    __shared__ unsigned short lds[4 * 16384];   // 128 KiB, 4 K-tile ring

    const int tid  = threadIdx.x;
    const int lane = tid & 63;
    const int w    = tid >> 6;       // wave 0..7
    const int wm   = w >> 2;         // 0..1  (M half)
    const int wn   = w & 3;          // 0..3  (N quarter)

    // XCD-aware bijective swizzle (grid % 8 == 0)
    const int ntn = N >> 8;
    const int chunk = gridDim.x >> 3;
    const int sw = (blockIdx.x & 7) * chunk + (blockIdx.x >> 3);
    const int bm = sw / ntn, bn = sw % ntn;

    // ---- staging source decode (inverse swizzle; LDS dest stays linear) ----
    size_t gOfs[2];
#pragma unroll
    for (int i = 0; i < 2; ++i) {
        int lp  = i * 512 + tid;
        int pr  = lp >> 2, ps = lp & 3;
        int row = pr ^ ((pr >> 2) & 1);      // logical row (involution)
        int s   = ps ^ (row & 3);            // logical 16B slot within row
        gOfs[i] = (size_t)row * K + s * 8;
    }
    const unsigned short* Ag = A + (size_t)(bm * 256) * K;
    const unsigned short* Bg = B + (size_t)(bn * 256) * K;

    // ---- ds_read fragment addresses (swizzled) ----
    const int ar  = lane & 15;
    const int kg  = lane >> 4;
    const int rsw = ar ^ ((ar >> 2) & 1);
    const int ssw = (kg ^ (ar & 3)) * 8;
    const int aoff = (wm * 128 + rsw) * 32 + ssw;          // + m*512
    const int boff = 8192 + (wn * 64 + rsw) * 32 + ssw;    // + n*512

    f32x4 acc[8][4];
#pragma unroll
    for (int m = 0; m < 8; ++m)
#pragma unroll
        for (int n = 0; n < 4; ++n)
            acc[m][n] = (f32x4){0.f, 0.f, 0.f, 0.f};

    const int NT = K >> 5;

    // ---- prologue: stage K-tiles 0,1,2 ----
#pragma unroll
    for (int tt = 0; tt < 3; ++tt) {
        unsigned short* dS = lds + tt * 16384 + w * 512;
        const unsigned short* sA = Ag + tt * 32;
        const unsigned short* sB = Bg + tt * 32;
        GLL(sA + gOfs[0], dS);
        GLL(sA + gOfs[1], dS + 4096);
        GLL(sB + gOfs[0], dS + 8192);
        GLL(sB + gOfs[1], dS + 12288);
    }
    asm volatile("s_waitcnt vmcnt(8)" ::: "memory");   // tile 0 landed (1,2 in flight)
    __builtin_amdgcn_s_barrier();

    // ---- main loop: 2 phases/K-tile, m201 shape, B reg-reuse across phases ----
    for (int t = 0; t < NT; ++t) {
        const unsigned short* bufc = lds + (t & 3) * 16384;
        const int ts = (t + 3 < NT) ? (t + 3) : (NT - 1);   // clamped tail re-stage
        unsigned short* dS = lds + ((t + 3) & 3) * 16384 + w * 512;
        const unsigned short* sA = Ag + ts * 32;
        const unsigned short* sB = Bg + ts * 32;

        bf16x8 a_[4], b_[4];
        // ---- phase 1 (mh=0): read A m0-3 + B n0-3 | stage A(t+3) | 16 MFMA ----
#pragma unroll
        for (int m = 0; m < 4; ++m) a_[m] = *(const bf16x8*)(bufc + aoff + m * 512);
#pragma unroll
        for (int n = 0; n < 4; ++n) b_[n] = *(const bf16x8*)(bufc + boff + n * 512);
        GLL(sA + gOfs[0], dS);
        GLL(sA + gOfs[1], dS + 4096);
        __builtin_amdgcn_s_barrier();
        asm volatile("s_waitcnt lgkmcnt(0)" ::: "memory");
        __builtin_amdgcn_s_setprio(1);
#pragma unroll
        for (int m = 0; m < 4; ++m)
#pragma unroll
            for (int n = 0; n < 4; ++n)
                acc[m][n] = __builtin_amdgcn_mfma_f32_16x16x32_bf16(a_[m], b_[n], acc[m][n], 0, 0, 0);
        __builtin_amdgcn_s_setprio(0);
        __builtin_amdgcn_s_barrier();

        // ---- phase 2 (mh=1): read A m4-7 (B reused) | stage B(t+3) | 16 MFMA ----
#pragma unroll
        for (int m = 0; m < 4; ++m) a_[m] = *(const bf16x8*)(bufc + aoff + (4 + m) * 512);
        GLL(sB + gOfs[0], dS + 8192);
        GLL(sB + gOfs[1], dS + 12288);
        __builtin_amdgcn_s_barrier();
        asm volatile("s_waitcnt lgkmcnt(0)" ::: "memory");
        __builtin_amdgcn_s_setprio(1);
#pragma unroll
        for (int m = 0; m < 4; ++m)
#pragma unroll
            for (int n = 0; n < 4; ++n)
                acc[4 + m][n] = __builtin_amdgcn_mfma_f32_16x16x32_bf16(a_[m], b_[n], acc[4 + m][n], 0, 0, 0);
        __builtin_amdgcn_s_setprio(0);
        // counted wait BEFORE barrier: own t+1 loads landed; t+2,t+3 stay in flight
        asm volatile("s_waitcnt vmcnt(8)" ::: "memory");
        __builtin_amdgcn_s_barrier();
    }

    // ---- epilogue: C/D layout col=lane&15, row=(lane>>4)*4+j  [m89-verified] ----
    const int row0 = bm * 256 + wm * 128 + (lane >> 4) * 4;
    const int col0 = bn * 256 + wn * 64 + (lane & 15);
#pragma unroll
    for (int n = 0; n < 4; ++n) {
        const int col = col0 + n * 16;
        const float bv = bias[col];
#pragma unroll
        for (int m = 0; m < 8; ++m) {
            const int rb = row0 + m * 16;
#pragma unroll
            for (int j = 0; j < 4; ++j) {
                const size_t idx = (size_t)(rb + j) * (size_t)N + col;
                float v = acc[m][n][j] + bv;
                if (EPI == 0) {
                    ((unsigned short*)Cv)[idx] = f2bf(v);
                } else if (EPI == 1) {
                    float g = bf2f(gbuf[idx]);
                    float s = g / (1.f + __expf(-g));   // silu(g)
                    ((unsigned short*)Cv)[idx] = f2bf(s * v);
                } else {
                    ((float*)Cv)[idx] = v;
                }
            }
        }
    }
}

// ---------------- launcher ----------------
extern "C" void kernel_launch(void* const* d_in, const int* in_sizes, int n_in,
                              void* d_out, int out_size, void* d_ws, size_t ws_size,
                              hipStream_t stream) {
    const float* x  = (const float*)d_in[0];   // (2,2048,4096)
    const float* wg = (const float*)d_in[1];   // (11008,4096)
    const float* bg = (const float*)d_in[2];
    const float* wu = (const float*)d_in[3];
    const float* bu = (const float*)d_in[4];
    const float* wd = (const float*)d_in[5];   // (4096,11008)
    const float* bd = (const float*)d_in[6];

    const size_t NX = (size_t)M_TOK * HID;     // 16,777,216
    const size_t NW = (size_t)INT_ * HID;      // 45,088,768 (== M_TOK*INT_)

    unsigned short* ws = (unsigned short*)d_ws;
    unsigned short* Xb = ws;                   // x bf16
    unsigned short* S1 = Xb + NX;              // Wg -> later t
    unsigned short* S2 = S1 + NW;              // g  -> later Wd
    unsigned short* S3 = S2 + NW;              // Wu
    // peak ws need: (NX + 3*NW)*2 = 304,087,040 bytes

    dim3 blk512(512);
    dim3 blk256(256);
    const int CG = 2048;

    cvt_f32_bf16<<<CG, blk256, 0, stream>>>(x,  Xb, (int)(NX / 4));
    cvt_f32_bf16<<<CG, blk256, 0, stream>>>(wg, S1, (int)(NW / 4));
    // gate: g = x @ Wg^T + bg  (bf16 -> S2)   grid 16*43=688 (688%8==0)
    gemm256<0><<<dim3(16 * 43), blk512, 0, stream>>>(Xb, S1, bg, (const unsigned short*)nullptr,
                                                     (void*)S2, M_TOK, INT_, HID);
    cvt_f32_bf16<<<CG, blk256, 0, stream>>>(wu, S3, (int)(NW / 4));
    // up + fuse: t = silu(g) * (x @ Wu^T + bu)  (bf16 -> S1, Wg dead)
    gemm256<1><<<dim3(16 * 43), blk512, 0, stream>>>(Xb, S3, bu, S2,
                                                     (void*)S1, M_TOK, INT_, HID);
    cvt_f32_bf16<<<CG, blk256, 0, stream>>>(wd, S2, (int)(NW / 4));
    // down: out = t @ Wd^T + bd  (fp32 -> d_out)  grid 16*16=256 (256%8==0)
    gemm256<2><<<dim3(16 * 16), blk512, 0, stream>>>(S1, S2, bd, (const unsigned short*)nullptr,
                                                     d_out, M_TOK, HID, INT_);
}

// Round 5
// 1237.816 us; speedup vs baseline: 1.0596x; 1.0596x over previous
//
#include <hip/hip_runtime.h>
#include <hip/hip_bf16.h>

// SwiGLU MLP: out = down( silu(x@Wg^T + bg) * (x@Wu^T + bu) ) + bd
// M=4096 tokens, H=4096, I=11008. fp32 in/out, bf16 MFMA compute.
// GEMM: 256x256 tile, BK=32, 8 waves, 4-deep LDS ring, counted vmcnt(8),
// 1 barrier/K-tile, drifting-wave phases (R3 schedule), 2x-unrolled main loop
// with ping-pong fragment registers (ZERO register copies), XOR-swizzled LDS,
// XCD-aware bijective block swizzle.

#define M_TOK 4096
#define HID   4096
#define INT_  11008

typedef __attribute__((ext_vector_type(8))) short bf16x8;
typedef __attribute__((ext_vector_type(4))) float f32x4;

__device__ __forceinline__ unsigned short f2bf(float f) {
    union { float f; unsigned int u; } a; a.f = f;
    unsigned int u = a.u;
    u += 0x7fff + ((u >> 16) & 1);   // RNE
    return (unsigned short)(u >> 16);
}

__device__ __forceinline__ float bf2f(unsigned short h) {
    union { unsigned int u; float f; } a; a.u = ((unsigned int)h) << 16;
    return a.f;
}

// ---------------- fp32 -> bf16 convert (vectorized, grid-stride) ----------------
__global__ void cvt_f32_bf16(const float* __restrict__ in, unsigned short* __restrict__ out, int n4) {
    int stride = gridDim.x * blockDim.x;
    for (int i = blockIdx.x * blockDim.x + threadIdx.x; i < n4; i += stride) {
        float4 v = ((const float4*)in)[i];
        ushort4 o;
        o.x = f2bf(v.x); o.y = f2bf(v.y); o.z = f2bf(v.z); o.w = f2bf(v.w);
        ((ushort4*)out)[i] = o;
    }
}

#define GLL(gsrc, ldst) \
    __builtin_amdgcn_global_load_lds( \
        (__attribute__((address_space(1))) void*)(gsrc), \
        (__attribute__((address_space(3))) void*)(ldst), 16, 0, 0)

// ---------------- 256x256-tile bf16 GEMM, C = A * B^T (+epilogue) ----------------
// A: M x K bf16 row-major; B: N x K bf16 row-major. M%256==0, N%256==0, K%64==0
// (NT even, >=4), grid divisible by 8.
// EPI 0: bf16 (acc+bias); EPI 1: bf16 silu(g)*(acc+bias); EPI 2: fp32 (acc+bias)
template<int EPI>
__global__ __launch_bounds__(512, 2)
void gemm256(const unsigned short* __restrict__ A,
             const unsigned short* __restrict__ B,
             const float* __restrict__ bias,
             const unsigned short* __restrict__ gbuf,
             void* __restrict__ Cv,
             int M, int N, int K) {
    __shared__ unsigned short lds[4 * 16384];   // 128 KiB, 4 K-tile ring

    const int tid  = threadIdx.x;
    const int lane = tid & 63;
    const int w    = tid >> 6;       // wave 0..7
    const int wm   = w >> 2;         // 0..1  (M half)
    const int wn   = w & 3;          // 0..3  (N quarter)

    // XCD-aware bijective swizzle (grid % 8 == 0)
    const int ntn = N >> 8;
    const int chunk = gridDim.x >> 3;
    const int sw = (blockIdx.x & 7) * chunk + (blockIdx.x >> 3);
    const int bm = sw / ntn, bn = sw % ntn;

    // ---- staging source decode (inverse swizzle; LDS dest stays linear) ----
    size_t gOfs[2];
#pragma unroll
    for (int i = 0; i < 2; ++i) {
        int lp  = i * 512 + tid;
        int pr  = lp >> 2, ps = lp & 3;
        int row = pr ^ ((pr >> 2) & 1);      // logical row (involution)
        int s   = ps ^ (row & 3);            // logical 16B slot within row
        gOfs[i] = (size_t)row * K + s * 8;
    }
    const unsigned short* Ag = A + (size_t)(bm * 256) * K;
    const unsigned short* Bg = B + (size_t)(bn * 256) * K;

    // ---- ds_read fragment addresses (swizzled) ----
    const int ar  = lane & 15;
    const int kg  = lane >> 4;
    const int rsw = ar ^ ((ar >> 2) & 1);
    const int ssw = (kg ^ (ar & 3)) * 8;
    const int aoff = (wm * 128 + rsw) * 32 + ssw;          // + m*512
    const int boff = 8192 + (wn * 64 + rsw) * 32 + ssw;    // + n*512

    f32x4 acc[8][4];
#pragma unroll
    for (int m = 0; m < 8; ++m)
#pragma unroll
        for (int n = 0; n < 4; ++n)
            acc[m][n] = (f32x4){0.f, 0.f, 0.f, 0.f};

    const int NT = K >> 5;   // even, >= 4

    // ---- prologue: stage K-tiles 0,1,2 ----
#pragma unroll
    for (int tt = 0; tt < 3; ++tt) {
        unsigned short* dS = lds + tt * 16384 + w * 512;
        const unsigned short* sA = Ag + tt * 32;
        const unsigned short* sB = Bg + tt * 32;
        GLL(sA + gOfs[0], dS);
        GLL(sA + gOfs[1], dS + 4096);
        GLL(sB + gOfs[0], dS + 8192);
        GLL(sB + gOfs[1], dS + 12288);
    }
    asm volatile("s_waitcnt vmcnt(8)" ::: "memory");   // tile 0 landed (1,2 in flight)
    __builtin_amdgcn_s_barrier();

    // ping-pong fragment registers (no copies, all statically indexed)
    bf16x8 a0, a1, a2, a3, bbA[4], bbB[4];
#pragma unroll
    for (int n = 0; n < 4; ++n) bbA[n] = *(const bf16x8*)(lds + boff + n * 512);
    a0 = *(const bf16x8*)(lds + aoff);
    a1 = *(const bf16x8*)(lds + aoff + 512);

#define MROW(mi, af, BB) \
    { _Pragma("unroll") \
      for (int n = 0; n < 4; ++n) \
          acc[mi][n] = __builtin_amdgcn_mfma_f32_16x16x32_bf16(af, BB[n], acc[mi][n], 0, 0, 0); }

    // One K-tile step. Consumes B-frags from BC, loads next tile's B into BN_.
    // A-frags rotate a0..a3 (p0 loads m2,m3; p1 loads m4,m5; p2 loads m6,m7;
    // p3 loads next tile's m0,m1). Zero register moves.
#define TILE_STEP(t, BC, BN_)                                                   \
    {                                                                           \
        const unsigned short* bufc = lds + ((t) & 3) * 16384;                   \
        const unsigned short* bufn = lds + (((t) + 1) & 3) * 16384;             \
        const int ts = ((t) + 3 < NT) ? ((t) + 3) : (NT - 1);                   \
        unsigned short* dS = lds + (((t) + 3) & 3) * 16384 + w * 512;           \
        const unsigned short* sA = Ag + (size_t)ts * 32;                        \
        const unsigned short* sB = Bg + (size_t)ts * 32;                        \
        /* p0: read m2,m3 | stage A#0 | MFMA m0,m1 */                           \
        a2 = *(const bf16x8*)(bufc + aoff + 2 * 512);                           \
        a3 = *(const bf16x8*)(bufc + aoff + 3 * 512);                           \
        GLL(sA + gOfs[0], dS);                                                  \
        __builtin_amdgcn_s_setprio(1);                                          \
        MROW(0, a0, BC); MROW(1, a1, BC);                                       \
        __builtin_amdgcn_s_setprio(0);                                          \
        /* p1: read m4,m5 | stage A#1 | MFMA m2,m3 */                           \
        a0 = *(const bf16x8*)(bufc + aoff + 4 * 512);                           \
        a1 = *(const bf16x8*)(bufc + aoff + 5 * 512);                           \
        GLL(sA + gOfs[1], dS + 4096);                                           \
        __builtin_amdgcn_s_setprio(1);                                          \
        MROW(2, a2, BC); MROW(3, a3, BC);                                       \
        __builtin_amdgcn_s_setprio(0);                                          \
        /* p2: read m6,m7 | stage B#0 | MFMA m4,m5 */                           \
        a2 = *(const bf16x8*)(bufc + aoff + 6 * 512);                           \
        a3 = *(const bf16x8*)(bufc + aoff + 7 * 512);                           \
        GLL(sB + gOfs[0], dS + 8192);                                           \
        __builtin_amdgcn_s_setprio(1);                                          \
        MROW(4, a0, BC); MROW(5, a1, BC);                                       \
        __builtin_amdgcn_s_setprio(0);                                          \
        /* stage B#1; drain own LDS reads; counted vmcnt; tile barrier */       \
        GLL(sB + gOfs[1], dS + 12288);                                          \
        asm volatile("s_waitcnt lgkmcnt(0)" ::: "memory");                      \
        asm volatile("s_waitcnt vmcnt(8)" ::: "memory");                        \
        __builtin_amdgcn_s_barrier();                                           \
        /* p3: read next-tile B + m0,m1 | MFMA m6,m7 */                         \
        BN_[0] = *(const bf16x8*)(bufn + boff);                                 \
        BN_[1] = *(const bf16x8*)(bufn + boff + 512);                           \
        BN_[2] = *(const bf16x8*)(bufn + boff + 1024);                          \
        BN_[3] = *(const bf16x8*)(bufn + boff + 1536);                          \
        a0 = *(const bf16x8*)(bufn + aoff);                                     \
        a1 = *(const bf16x8*)(bufn + aoff + 512);                               \
        __builtin_amdgcn_s_setprio(1);                                          \
        MROW(6, a2, BC); MROW(7, a3, BC);                                       \
        __builtin_amdgcn_s_setprio(0);                                          \
    }

    // ---- main loop: 2x unrolled, B-frag arrays swap roles (no copies) ----
    for (int t = 0; t < NT; t += 2) {
        TILE_STEP(t,     bbA, bbB);
        TILE_STEP(t + 1, bbB, bbA);
    }
#undef TILE_STEP
#undef MROW

    // ---- epilogue: C/D layout col=lane&15, row=(lane>>4)*4+j  [m89-verified] ----
    const int row0 = bm * 256 + wm * 128 + (lane >> 4) * 4;
    const int col0 = bn * 256 + wn * 64 + (lane & 15);
#pragma unroll
    for (int n = 0; n < 4; ++n) {
        const int col = col0 + n * 16;
        const float bv = bias[col];
#pragma unroll
        for (int m = 0; m < 8; ++m) {
            const int rb = row0 + m * 16;
#pragma unroll
            for (int j = 0; j < 4; ++j) {
                const size_t idx = (size_t)(rb + j) * (size_t)N + col;
                float v = acc[m][n][j] + bv;
                if (EPI == 0) {
                    ((unsigned short*)Cv)[idx] = f2bf(v);
                } else if (EPI == 1) {
                    float g = bf2f(gbuf[idx]);
                    float s = g / (1.f + __expf(-g));   // silu(g)
                    ((unsigned short*)Cv)[idx] = f2bf(s * v);
                } else {
                    ((float*)Cv)[idx] = v;
                }
            }
        }
    }
}

// ---------------- launcher ----------------
extern "C" void kernel_launch(void* const* d_in, const int* in_sizes, int n_in,
                              void* d_out, int out_size, void* d_ws, size_t ws_size,
                              hipStream_t stream) {
    const float* x  = (const float*)d_in[0];   // (2,2048,4096)
    const float* wg = (const float*)d_in[1];   // (11008,4096)
    const float* bg = (const float*)d_in[2];
    const float* wu = (const float*)d_in[3];
    const float* bu = (const float*)d_in[4];
    const float* wd = (const float*)d_in[5];   // (4096,11008)
    const float* bd = (const float*)d_in[6];

    const size_t NX = (size_t)M_TOK * HID;     // 16,777,216
    const size_t NW = (size_t)INT_ * HID;      // 45,088,768 (== M_TOK*INT_)

    unsigned short* ws = (unsigned short*)d_ws;
    unsigned short* Xb = ws;                   // x bf16
    unsigned short* S1 = Xb + NX;              // Wg -> later t
    unsigned short* S2 = S1 + NW;              // g  -> later Wd
    unsigned short* S3 = S2 + NW;              // Wu
    // peak ws need: (NX + 3*NW)*2 = 304,087,040 bytes

    dim3 blk512(512);
    dim3 blk256(256);
    const int CG = 2048;

    cvt_f32_bf16<<<CG, blk256, 0, stream>>>(x,  Xb, (int)(NX / 4));
    cvt_f32_bf16<<<CG, blk256, 0, stream>>>(wg, S1, (int)(NW / 4));
    // gate: g = x @ Wg^T + bg  (bf16 -> S2)   grid 16*43=688 (688%8==0)
    gemm256<0><<<dim3(16 * 43), blk512, 0, stream>>>(Xb, S1, bg, (const unsigned short*)nullptr,
                                                     (void*)S2, M_TOK, INT_, HID);
    cvt_f32_bf16<<<CG, blk256, 0, stream>>>(wu, S3, (int)(NW / 4));
    // up + fuse: t = silu(g) * (x @ Wu^T + bu)  (bf16 -> S1, Wg dead)
    gemm256<1><<<dim3(16 * 43), blk512, 0, stream>>>(Xb, S3, bu, S2,
                                                     (void*)S1, M_TOK, INT_, HID);
    cvt_f32_bf16<<<CG, blk256, 0, stream>>>(wd, S2, (int)(NW / 4));
    // down: out = t @ Wd^T + bd  (fp32 -> d_out)  grid 16*16=256 (256%8==0)
    gemm256<2><<<dim3(16 * 16), blk512, 0, stream>>>(S1, S2, bd, (const unsigned short*)nullptr,
                                                     d_out, M_TOK, HID, INT_);
}

// Round 6
// 1231.559 us; speedup vs baseline: 1.0650x; 1.0051x over previous
//
#include <hip/hip_runtime.h>
#include <hip/hip_bf16.h>

// SwiGLU MLP: out = down( silu(x@Wg^T + bg) * (x@Wu^T + bu) ) + bd
// M=4096 tokens, H=4096, I=11008. fp32 in/out, bf16 MFMA compute.
// GEMM: 256x256 tile, BK=32, 8 waves, 4-deep LDS ring, counted vmcnt(4),
// 1 barrier/K-tile, 2 phases/tile with 16-MFMA bursts (reads issued one full
// burst ahead), XOR-swizzled LDS, XCD-aware bijective block swizzle.

#define M_TOK 4096
#define HID   4096
#define INT_  11008

typedef __attribute__((ext_vector_type(8))) short bf16x8;
typedef __attribute__((ext_vector_type(4))) float f32x4;

__device__ __forceinline__ unsigned short f2bf(float f) {
    union { float f; unsigned int u; } a; a.f = f;
    unsigned int u = a.u;
    u += 0x7fff + ((u >> 16) & 1);   // RNE
    return (unsigned short)(u >> 16);
}

__device__ __forceinline__ float bf2f(unsigned short h) {
    union { unsigned int u; float f; } a; a.u = ((unsigned int)h) << 16;
    return a.f;
}

// ---------------- fp32 -> bf16 convert (vectorized, grid-stride) ----------------
__global__ void cvt_f32_bf16(const float* __restrict__ in, unsigned short* __restrict__ out, int n4) {
    int stride = gridDim.x * blockDim.x;
    for (int i = blockIdx.x * blockDim.x + threadIdx.x; i < n4; i += stride) {
        float4 v = ((const float4*)in)[i];
        ushort4 o;
        o.x = f2bf(v.x); o.y = f2bf(v.y); o.z = f2bf(v.z); o.w = f2bf(v.w);
        ((ushort4*)out)[i] = o;
    }
}

#define GLL(gsrc, ldst) \
    __builtin_amdgcn_global_load_lds( \
        (__attribute__((address_space(1))) void*)(gsrc), \
        (__attribute__((address_space(3))) void*)(ldst), 16, 0, 0)

// ---------------- 256x256-tile bf16 GEMM, C = A * B^T (+epilogue) ----------------
// A: M x K bf16 row-major; B: N x K bf16 row-major. M%256==0, N%256==0, K%32==0,
// K/32 >= 4, grid divisible by 8.
// EPI 0: bf16 (acc+bias); EPI 1: bf16 silu(g)*(acc+bias); EPI 2: fp32 (acc+bias)
template<int EPI>
__global__ __launch_bounds__(512, 2)
void gemm256(const unsigned short* __restrict__ A,
             const unsigned short* __restrict__ B,
             const float* __restrict__ bias,
             const unsigned short* __restrict__ gbuf,
             void* __restrict__ Cv,
             int M, int N, int K) {
    __shared__ unsigned short lds[4 * 16384];   // 128 KiB, 4 K-tile ring

    const int tid  = threadIdx.x;
    const int lane = tid & 63;
    const int w    = tid >> 6;       // wave 0..7
    const int wm   = w >> 2;         // 0..1  (M half)
    const int wn   = w & 3;          // 0..3  (N quarter)

    // XCD-aware bijective swizzle (grid % 8 == 0)
    const int ntn = N >> 8;
    const int chunk = gridDim.x >> 3;
    const int sw = (blockIdx.x & 7) * chunk + (blockIdx.x >> 3);
    const int bm = sw / ntn, bn = sw % ntn;

    // ---- staging source decode (inverse swizzle; LDS dest stays linear) ----
    size_t gOfs[2];
#pragma unroll
    for (int i = 0; i < 2; ++i) {
        int lp  = i * 512 + tid;
        int pr  = lp >> 2, ps = lp & 3;
        int row = pr ^ ((pr >> 2) & 1);      // logical row (involution)
        int s   = ps ^ (row & 3);            // logical 16B slot within row
        gOfs[i] = (size_t)row * K + s * 8;
    }
    const unsigned short* Ag = A + (size_t)(bm * 256) * K;
    const unsigned short* Bg = B + (size_t)(bn * 256) * K;

    // ---- ds_read fragment addresses (swizzled) ----
    const int ar  = lane & 15;
    const int kg  = lane >> 4;
    const int rsw = ar ^ ((ar >> 2) & 1);
    const int ssw = (kg ^ (ar & 3)) * 8;
    const int aoff = (wm * 128 + rsw) * 32 + ssw;          // + m*512
    const int boff = 8192 + (wn * 64 + rsw) * 32 + ssw;    // + n*512

    f32x4 acc[8][4];
#pragma unroll
    for (int m = 0; m < 8; ++m)
#pragma unroll
        for (int n = 0; n < 4; ++n)
            acc[m][n] = (f32x4){0.f, 0.f, 0.f, 0.f};

    const int NT = K >> 5;

    // ---- prologue: stage K-tiles 0,1,2 ----
#pragma unroll
    for (int tt = 0; tt < 3; ++tt) {
        unsigned short* dS = lds + tt * 16384 + w * 512;
        const unsigned short* sA = Ag + tt * 32;
        const unsigned short* sB = Bg + tt * 32;
        GLL(sA + gOfs[0], dS);
        GLL(sA + gOfs[1], dS + 4096);
        GLL(sB + gOfs[0], dS + 8192);
        GLL(sB + gOfs[1], dS + 12288);
    }
    // tiles 0,1 landed (only tile 2's 4 loads may remain in flight)
    asm volatile("s_waitcnt vmcnt(4)" ::: "memory");
    __builtin_amdgcn_s_barrier();

    // fragment registers: AX = a0-3(cur), AY = a4-7(cur), BC = B(cur)
    bf16x8 AX[4], AY[4], BC[4];
#pragma unroll
    for (int m = 0; m < 4; ++m) AX[m] = *(const bf16x8*)(lds + aoff + m * 512);
#pragma unroll
    for (int n = 0; n < 4; ++n) BC[n] = *(const bf16x8*)(lds + boff + n * 512);

#define BURST16(ACB, ASET) \
    { __builtin_amdgcn_s_setprio(1); \
      _Pragma("unroll") \
      for (int mfi = 0; mfi < 4; ++mfi) { \
        _Pragma("unroll") \
        for (int n = 0; n < 4; ++n) \
            acc[(ACB) + mfi][n] = __builtin_amdgcn_mfma_f32_16x16x32_bf16( \
                ASET[mfi], BC[n], acc[(ACB) + mfi][n], 0, 0, 0); } \
      __builtin_amdgcn_s_setprio(0); }

    // ---- main loop: 2 phases/tile, 16-MFMA bursts, reads one burst ahead ----
    for (int t = 0; t < NT; ++t) {
        const unsigned short* bufc = lds + (t & 3) * 16384;
        const unsigned short* bufn = lds + ((t + 1) & 3) * 16384;
        const int ts = (t + 3 < NT) ? (t + 3) : (NT - 1);   // clamped tail re-stage
        unsigned short* dS = lds + ((t + 3) & 3) * 16384 + w * 512;
        const unsigned short* sA = Ag + (size_t)ts * 32;
        const unsigned short* sB = Bg + (size_t)ts * 32;

        // PH_a: read a4-7(t) | stage A(t+3) | 16 MFMA: m0-3 x B(t)
        AY[0] = *(const bf16x8*)(bufc + aoff + 4 * 512);
        AY[1] = *(const bf16x8*)(bufc + aoff + 5 * 512);
        AY[2] = *(const bf16x8*)(bufc + aoff + 6 * 512);
        AY[3] = *(const bf16x8*)(bufc + aoff + 7 * 512);
        GLL(sA + gOfs[0], dS);
        GLL(sA + gOfs[1], dS + 4096);
        BURST16(0, AX);

        // PH_b: read a0-3(t+1) | stage B(t+3) | 16 MFMA: m4-7 x B(t) | read B(t+1)
        AX[0] = *(const bf16x8*)(bufn + aoff);
        AX[1] = *(const bf16x8*)(bufn + aoff + 512);
        AX[2] = *(const bf16x8*)(bufn + aoff + 2 * 512);
        AX[3] = *(const bf16x8*)(bufn + aoff + 3 * 512);
        GLL(sB + gOfs[0], dS + 8192);
        GLL(sB + gOfs[1], dS + 12288);
        BURST16(4, AY);
        BC[0] = *(const bf16x8*)(bufn + boff);
        BC[1] = *(const bf16x8*)(bufn + boff + 512);
        BC[2] = *(const bf16x8*)(bufn + boff + 1024);
        BC[3] = *(const bf16x8*)(bufn + boff + 1536);

        // counted wait: forces tile t+1 fully landed (formal cross-wave
        // visibility after the barrier); t+2/t+3 stay in flight.
        asm volatile("s_waitcnt vmcnt(4)" ::: "memory");
        __builtin_amdgcn_s_barrier();
    }
#undef BURST16

    // ---- epilogue: C/D layout col=lane&15, row=(lane>>4)*4+j  [m89-verified] ----
    const int row0 = bm * 256 + wm * 128 + (lane >> 4) * 4;
    const int col0 = bn * 256 + wn * 64 + (lane & 15);
#pragma unroll
    for (int n = 0; n < 4; ++n) {
        const int col = col0 + n * 16;
        const float bv = bias[col];
#pragma unroll
        for (int m = 0; m < 8; ++m) {
            const int rb = row0 + m * 16;
#pragma unroll
            for (int j = 0; j < 4; ++j) {
                const size_t idx = (size_t)(rb + j) * (size_t)N + col;
                float v = acc[m][n][j] + bv;
                if (EPI == 0) {
                    ((unsigned short*)Cv)[idx] = f2bf(v);
                } else if (EPI == 1) {
                    float g = bf2f(gbuf[idx]);
                    float s = g / (1.f + __expf(-g));   // silu(g)
                    ((unsigned short*)Cv)[idx] = f2bf(s * v);
                } else {
                    ((float*)Cv)[idx] = v;
                }
            }
        }
    }
}

// ---------------- launcher ----------------
extern "C" void kernel_launch(void* const* d_in, const int* in_sizes, int n_in,
                              void* d_out, int out_size, void* d_ws, size_t ws_size,
                              hipStream_t stream) {
    const float* x  = (const float*)d_in[0];   // (2,2048,4096)
    const float* wg = (const float*)d_in[1];   // (11008,4096)
    const float* bg = (const float*)d_in[2];
    const float* wu = (const float*)d_in[3];
    const float* bu = (const float*)d_in[4];
    const float* wd = (const float*)d_in[5];   // (4096,11008)
    const float* bd = (const float*)d_in[6];

    const size_t NX = (size_t)M_TOK * HID;     // 16,777,216
    const size_t NW = (size_t)INT_ * HID;      // 45,088,768 (== M_TOK*INT_)

    unsigned short* ws = (unsigned short*)d_ws;
    unsigned short* Xb = ws;                   // x bf16
    unsigned short* S1 = Xb + NX;              // Wg -> later t
    unsigned short* S2 = S1 + NW;              // g  -> later Wd
    unsigned short* S3 = S2 + NW;              // Wu
    // peak ws need: (NX + 3*NW)*2 = 304,087,040 bytes

    dim3 blk512(512);
    dim3 blk256(256);
    const int CG = 2048;

    cvt_f32_bf16<<<CG, blk256, 0, stream>>>(x,  Xb, (int)(NX / 4));
    cvt_f32_bf16<<<CG, blk256, 0, stream>>>(wg, S1, (int)(NW / 4));
    // gate: g = x @ Wg^T + bg  (bf16 -> S2)   grid 16*43=688 (688%8==0)
    gemm256<0><<<dim3(16 * 43), blk512, 0, stream>>>(Xb, S1, bg, (const unsigned short*)nullptr,
                                                     (void*)S2, M_TOK, INT_, HID);
    cvt_f32_bf16<<<CG, blk256, 0, stream>>>(wu, S3, (int)(NW / 4));
    // up + fuse: t = silu(g) * (x @ Wu^T + bu)  (bf16 -> S1, Wg dead)
    gemm256<1><<<dim3(16 * 43), blk512, 0, stream>>>(Xb, S3, bu, S2,
                                                     (void*)S1, M_TOK, INT_, HID);
    cvt_f32_bf16<<<CG, blk256, 0, stream>>>(wd, S2, (int)(NW / 4));
    // down: out = t @ Wd^T + bd  (fp32 -> d_out)  grid 16*16=256 (256%8==0)
    gemm256<2><<<dim3(16 * 16), blk512, 0, stream>>>(S1, S2, bd, (const unsigned short*)nullptr,
                                                     d_out, M_TOK, HID, INT_);
}